// Round 1
// baseline (191.113 us; speedup 1.0000x reference)
//
#include <hip/hip_runtime.h>
#include <math.h>

#define B_  2
#define S_  2048
#define E_  1024
#define H_  16
#define HD_ 64
#define N3_ 3072
#define M_  (B_*S_)   // 4096

typedef _Float16 h8  __attribute__((ext_vector_type(8)));
typedef _Float16 h4  __attribute__((ext_vector_type(4)));
typedef float    f4  __attribute__((ext_vector_type(4)));
typedef float    fv16 __attribute__((ext_vector_type(16)));

typedef __attribute__((address_space(3))) unsigned int       lds_u32;
typedef const __attribute__((address_space(1))) unsigned int glob_u32;

// async global->LDS, 16B/lane; global addr per-lane, LDS dest = base + lane*16.
__device__ __forceinline__ void gld16(const void* g, void* l) {
    __builtin_amdgcn_global_load_lds((glob_u32*)g, (lds_u32*)l, 16, 0, 0);
}
__device__ __forceinline__ float exp2_hw(float x) { return __builtin_amdgcn_exp2f(x); }

#define QSCALE 0.18033688011112042f   // log2(e)/8

// ---------------- kernel 0b: x fp32 -> f16 ----------------
__global__ void cvt_x_kernel(const float* __restrict__ x, _Float16* __restrict__ x16) {
    int i = (blockIdx.x * 256 + threadIdx.x) * 8;
    float4 u = *(const float4*)&x[i];
    float4 v = *(const float4*)&x[i + 4];
    h8 o;
    o[0] = (_Float16)u.x; o[1] = (_Float16)u.y; o[2] = (_Float16)u.z; o[3] = (_Float16)u.w;
    o[4] = (_Float16)v.x; o[5] = (_Float16)v.y; o[6] = (_Float16)v.z; o[7] = (_Float16)v.w;
    *(h8*)&x16[i] = o;
}

// ---------------- kernel 0c: W [K][N] fp32 -> Wt [N][K] f16 ----------------
__global__ __launch_bounds__(256) void transpose_w_kernel(
        const float* __restrict__ W, _Float16* __restrict__ Wt) {
    __shared__ float T[64][65];
    int k0 = blockIdx.x * 64, n0 = blockIdx.y * 64;
    int tid = threadIdx.x;
    int r = tid >> 4, c4 = (tid & 15) * 4;
#pragma unroll
    for (int i = 0; i < 4; i++) {
        int row = r + i * 16;
        float4 u = *(const float4*)&W[(size_t)(k0 + row) * N3_ + n0 + c4];
        T[c4 + 0][row] = u.x; T[c4 + 1][row] = u.y;
        T[c4 + 2][row] = u.z; T[c4 + 3][row] = u.w;
    }
    __syncthreads();
#pragma unroll
    for (int i = 0; i < 4; i++) {
        int rn = r + i * 16;
        h4 p;
        p[0] = (_Float16)T[rn][c4 + 0]; p[1] = (_Float16)T[rn][c4 + 1];
        p[2] = (_Float16)T[rn][c4 + 2]; p[3] = (_Float16)T[rn][c4 + 3];
        *(h4*)&Wt[(size_t)(n0 + rn) * E_ + k0 + c4] = p;
    }
}

// ---------------- kernel 1: QKV GEMM, 32x32x16, 2-stage pipelined ----------
// BM=128, BN=192 (one head q|k|v), BK=64, wave = 64m x 96n.
// Swizzle: batch j stores chunk (lane&7)^(lane>>3)^(j&7); read c^(R&7)^((R>>3)&7).
__global__ __launch_bounds__(256, 2) void qkv_gemm32(
        const _Float16* __restrict__ x16, const _Float16* __restrict__ wt,
        const float* __restrict__ bq, const float* __restrict__ w,
        _Float16* __restrict__ qws, _Float16* __restrict__ kws,
        _Float16* __restrict__ vtws) {
    __shared__ __align__(16) _Float16 Ab[2][128 * 64];   // 32 KB
    __shared__ __align__(16) _Float16 Wb[2][192 * 64];   // 48 KB

    int tid = threadIdx.x;
    int wid = tid >> 6, lane = tid & 63;
    int l31 = lane & 31, hi = lane >> 5, l7 = l31 & 7;
    int srow = lane >> 3;
    int wm = wid & 1, wn = wid >> 1;

    int L = blockIdx.x;
    int head = 2 * (L & 7) + (L >> 8);   // 2 heads per XCD
    int mb = (L >> 3) & 31;
    int m0 = mb * 128;
    int n0 = head * 192;
    int b = m0 >> 11;
    int bh = b * H_ + head;
    int sblk = m0 & 2047;

    // bias folded into acc init
    fv16 acc[2][3];
#pragma unroll
    for (int ntl = 0; ntl < 3; ntl++) {
        int n_abs = wn * 96 + ntl * 32;
        int which = n_abs >> 6;
        fv16 ini;
        if (which == 2) {
            float bb = bq[n0 + n_abs + l31];
#pragma unroll
            for (int r = 0; r < 16; r++) ini[r] = bb;
        } else {
#pragma unroll
            for (int g = 0; g < 4; g++) {
                f4 bv = *(const f4*)&bq[n0 + n_abs + 8 * g + 4 * hi];
#pragma unroll
                for (int j = 0; j < 4; j++) ini[4 * g + j] = bv[j];
            }
        }
        acc[0][ntl] = ini; acc[1][ntl] = ini;
    }

    auto stage = [&](int t, int bf) {
        int k0 = t * 64;
#pragma unroll
        for (int j = 0; j < 4; j++) {
            int batch = wid * 4 + j;           // 0..15
            int row = batch * 8 + srow;
            int ch = (lane & 7) ^ srow ^ (batch & 7);
            gld16(&x16[(size_t)(m0 + row) * E_ + k0 + ch * 8], &Ab[bf][batch * 8 * 64]);
        }
#pragma unroll
        for (int j = 0; j < 6; j++) {
            int batch = wid * 6 + j;           // 0..23
            int row = batch * 8 + srow;
            int ch = (lane & 7) ^ srow ^ (batch & 7);
            gld16(&wt[(size_t)(n0 + row) * E_ + k0 + ch * 8], &Wb[bf][batch * 8 * 64]);
        }
    };

    stage(0, 0);

    for (int t = 0; t < 16; t++) {
        int bf = t & 1;
        __syncthreads();                  // drains DMA of tile t, fences buffers
        if (t < 15) stage(t + 1, bf ^ 1); // prefetch overlaps compute below
#pragma unroll
        for (int step = 0; step < 4; step++) {
            h8 af[2], wf[3];
#pragma unroll
            for (int mt = 0; mt < 2; mt++) {
                int R = wm * 64 + mt * 32 + l31;
                int ph = ((2 * step + hi) ^ l7 ^ ((mt * 4 + (l31 >> 3)) & 7)) * 8;
                af[mt] = *(const h8*)&Ab[bf][R * 64 + ph];
            }
#pragma unroll
            for (int ntl = 0; ntl < 3; ntl++) {
                int R = wn * 96 + ntl * 32 + l31;
                int ph = ((2 * step + hi) ^ l7 ^ ((wn * 12 + ntl * 4 + (l31 >> 3)) & 7)) * 8;
                wf[ntl] = *(const h8*)&Wb[bf][R * 64 + ph];
            }
#pragma unroll
            for (int ntl = 0; ntl < 3; ntl++) {
                bool isv = (wn == 1) && (ntl >= 1);
#pragma unroll
                for (int mt = 0; mt < 2; mt++) {
                    if (isv)
                        acc[mt][ntl] = __builtin_amdgcn_mfma_f32_32x32x16_f16(af[mt], wf[ntl], acc[mt][ntl], 0, 0, 0);
                    else
                        acc[mt][ntl] = __builtin_amdgcn_mfma_f32_32x32x16_f16(wf[ntl], af[mt], acc[mt][ntl], 0, 0, 0);
                }
            }
        }
    }

    // epilogue
#pragma unroll
    for (int ntl = 0; ntl < 3; ntl++) {
        int n_abs = wn * 96 + ntl * 32;
        int which = n_abs >> 6;
#pragma unroll
        for (int mt = 0; mt < 2; mt++) {
            if (which == 2) {
                // D rows = s, cols = d; V' = acc * w[s]; store Vt[d][s]
                int d = (n_abs & 63) + l31;
#pragma unroll
                for (int g = 0; g < 4; g++) {
                    int soff = wm * 64 + mt * 32 + 8 * g + 4 * hi;
                    f4 wf4 = *(const f4*)&w[m0 + soff];
                    h4 p;
#pragma unroll
                    for (int j = 0; j < 4; j++)
                        p[j] = (_Float16)(acc[mt][ntl][4 * g + j] * wf4[j]);
                    *(h4*)&vtws[((size_t)bh * 64 + d) * S_ + sblk + soff] = p;
                }
            } else {
                // D rows = d, cols = s; store [s][d]
                _Float16* dst = (which == 0) ? qws : kws;
                float scale = (which == 0) ? QSCALE : 1.0f;
                int s = sblk + wm * 64 + mt * 32 + l31;
#pragma unroll
                for (int g = 0; g < 4; g++) {
                    int d0 = (n_abs & 63) + 8 * g + 4 * hi;
                    h4 p;
#pragma unroll
                    for (int j = 0; j < 4; j++)
                        p[j] = (_Float16)(acc[mt][ntl][4 * g + j] * scale);
                    *(h4*)&dst[((size_t)bh * S_ + s) * 64 + d0] = p;
                }
            }
        }
    }
}

// ---------------- kernel 2: flash attention, K-split in-block ----
// Block = 512 threads (8 waves), 128 q. Waves 0-3: keys [0,1024);
// waves 4-7: keys [1024,2048). Each wave owns 32 q (q = lane&31),
// softmax state lane-local; halves merged at the end through LDS.
// 16 k-tiles of 64 per half, double-buffered staging (64 KB LDS).
// w row read from global (L1-resident broadcast, off critical path).
__global__ __launch_bounds__(512, 4) void attn_kernel(
        const _Float16* __restrict__ q, const _Float16* __restrict__ k,
        const _Float16* __restrict__ vt, const float* __restrict__ w,
        float* __restrict__ out) {
    __shared__ __align__(16) _Float16 Kb[2][2][64 * 64];   // [half][buf] 32 KB
    __shared__ __align__(16) _Float16 Vb[2][2][64 * 64];   // [half][buf] 32 KB

    int tid = threadIdx.x;
    int wid = tid >> 6, lane = tid & 63;
    int l31 = lane & 31, hi = lane >> 5, l7 = l31 & 7;
    int srow = lane >> 3;
    int s = wid >> 2;        // k-half this wave computes
    int w4 = wid & 3;        // q-group (32 q each)
    int L = blockIdx.x;
    int bh = (L & 7) + 8 * (L >> 7);    // 16 q-tiles of a bh per XCD
    int qt = (L >> 3) & 15;
    int q0 = qt * 128;
    int b = bh >> 4, h = bh & 15;

    const _Float16* qbase = q + (size_t)bh * S_ * HD_;
    const _Float16* kbase = k + (size_t)bh * S_ * HD_;
    const _Float16* vbase = vt + (size_t)bh * HD_ * S_;
    const float* wbase = w + (size_t)b * S_;

    // staging role: wave wid stages 4 of the 32 1KB-batches per step.
    // wid -> (half = wid>>2, kv = (wid>>1)&1, batches (wid&1)*4 .. +3)
    int skv = (wid >> 1) & 1;
    int bt0 = (wid & 1) * 4;

    auto stage = [&](int t, int bf) {
        int k0 = (s * 16 + t) * 64;
#pragma unroll
        for (int j = 0; j < 4; j++) {
            int bt = bt0 + j;                  // 0..7 within tile
            int row = bt * 8 + srow;
            int ch = l7 ^ srow ^ bt;
            if (skv == 0)
                gld16(&kbase[(size_t)(k0 + row) * 64 + ch * 8], &Kb[s][bf][bt * 8 * 64]);
            else
                gld16(&vbase[(size_t)row * S_ + k0 + ch * 8], &Vb[s][bf][bt * 8 * 64]);
        }
    };

    stage(0, 0);

    int qrow = q0 + w4 * 32 + l31;
    h8 qf[4];
#pragma unroll
    for (int step = 0; step < 4; step++)
        qf[step] = *(const h8*)&qbase[(size_t)qrow * 64 + 16 * step + 8 * hi];

    fv16 o[2];
    o[0] = (fv16)0.0f; o[1] = (fv16)0.0f;
    float m_r = -INFINITY, l_r = 0.0f;

    for (int t = 0; t < 16; t++) {
        int bf = t & 1;
        __syncthreads();                    // drains DMA of step t
        if (t < 15) stage(t + 1, bf ^ 1);   // overlaps compute below

        // ---- S^T = K*Q^T : rows k, cols q=l31 ----
        fv16 st[2];
        st[0] = (fv16)0.0f; st[1] = (fv16)0.0f;
#pragma unroll
        for (int step = 0; step < 4; step++) {
#pragma unroll
            for (int kt2 = 0; kt2 < 2; kt2++) {
                int R = kt2 * 32 + l31;
                int ph = ((2 * step + hi) ^ l7 ^ ((kt2 * 4 + (l31 >> 3)) & 7)) * 8;
                h8 kf = *(const h8*)&Kb[s][bf][R * 64 + ph];
                st[kt2] = __builtin_amdgcn_mfma_f32_32x32x16_f16(kf, qf[step], st[kt2], 0, 0, 0);
            }
        }

        // ---- online softmax (base 2), lane-local state (q = l31) ----
        int k0 = (s * 16 + t) * 64;
        float rm = -INFINITY;
#pragma unroll
        for (int kt2 = 0; kt2 < 2; kt2++)
#pragma unroll
            for (int r = 0; r < 16; r++) rm = fmaxf(rm, st[kt2][r]);
        rm = fmaxf(rm, __shfl_xor(rm, 32));
        float mnew = fmaxf(m_r, rm);
        float rs = 0.0f;
        h4 pf[2][4];
#pragma unroll
        for (int kt2 = 0; kt2 < 2; kt2++)
#pragma unroll
            for (int g = 0; g < 4; g++) {
                f4 wv = *(const f4*)&wbase[k0 + kt2 * 32 + 8 * g + 4 * hi];
                f4 e;
#pragma unroll
                for (int j = 0; j < 4; j++) {
                    float ev = exp2_hw(st[kt2][4 * g + j] - mnew);
                    e[j] = ev;
                    rs += ev * wv[j];
                }
                h4 p;
                p[0] = (_Float16)e[0]; p[1] = (_Float16)e[1];
                p[2] = (_Float16)e[2]; p[3] = (_Float16)e[3];
                pf[kt2][g] = p;
            }
        rs += __shfl_xor(rs, 32);
        float alpha = exp2_hw(m_r - mnew);
        m_r = mnew;
        l_r = l_r * alpha + rs;
        o[0] = o[0] * alpha;
        o[1] = o[1] * alpha;

        // ---- O^T += V'^T * P (32x32x8: B k-stripe matches C regs) ----
#pragma unroll
        for (int kt2 = 0; kt2 < 2; kt2++)
#pragma unroll
            for (int g = 0; g < 4; g++) {
                int c = 4 * kt2 + g;
#pragma unroll
                for (int dt = 0; dt < 2; dt++) {
                    int R = dt * 32 + l31;
                    int ph = (c ^ l7 ^ ((dt * 4 + (l31 >> 3)) & 7)) * 8 + hi * 4;
                    h4 vf = *(const h4*)&Vb[s][bf][R * 64 + ph];
                    o[dt] = __builtin_amdgcn_mfma_f32_32x32x8f16(vf, pf[kt2][g], o[dt], 0, 0, 0);
                }
            }
    }

    // ---- cross-half merge through LDS (reuses tile buffers) ----
    float* mO = (float*)&Kb[0][0][0];    // [64 d][128 q] fp32 = 32 KB
    float* mML = (float*)&Vb[0][0][0];   // [128 q][m,l]
    int qloc = w4 * 32 + l31;

    __syncthreads();                     // all tile reads done; safe to overwrite
    if (s == 1) {
#pragma unroll
        for (int dt = 0; dt < 2; dt++)
#pragma unroll
            for (int r = 0; r < 16; r++) {
                int d = dt * 32 + (r & 3) + 8 * (r >> 2) + 4 * hi;
                mO[d * 128 + qloc] = o[dt][r];
            }
        if (hi == 0) {
            mML[qloc * 2] = m_r;
            mML[qloc * 2 + 1] = l_r;
        }
    }
    __syncthreads();
    if (s == 0) {
        float m2 = mML[qloc * 2], l2 = mML[qloc * 2 + 1];
        float mm = fmaxf(m_r, m2);
        float a0 = exp2_hw(m_r - mm), a1 = exp2_hw(m2 - mm);
        float linv = 1.0f / (l_r * a0 + l2 * a1);
        a0 *= linv; a1 *= linv;
        float* obase = &out[((size_t)(b * S_ + q0 + qloc)) * E_ + h * 64];
#pragma unroll
        for (int dt = 0; dt < 2; dt++)
#pragma unroll
            for (int g = 0; g < 4; g++) {
                int d0 = dt * 32 + 8 * g + 4 * hi;
                f4 ov;
#pragma unroll
                for (int j = 0; j < 4; j++)
                    ov[j] = o[dt][4 * g + j] * a0 + mO[(d0 + j) * 128 + qloc] * a1;
                *(f4*)&obase[d0] = ov;
            }
    }
}

extern "C" void kernel_launch(void* const* d_in, const int* in_sizes, int n_in,
                              void* d_out, int out_size, void* d_ws, size_t ws_size,
                              hipStream_t stream) {
    const float* x  = (const float*)d_in[0];
    const float* w  = (const float*)d_in[1];
    const float* Wq = (const float*)d_in[2];
    const float* bq = (const float*)d_in[3];
    float* out = (float*)d_out;

    char* p = (char*)d_ws;
    _Float16* x16 = (_Float16*)p;              p += (size_t)M_ * E_ * 2;
    _Float16* wt  = (_Float16*)p;              p += (size_t)E_ * N3_ * 2;
    _Float16* qb  = (_Float16*)p;              p += (size_t)M_ * E_ * 2;
    _Float16* kb  = (_Float16*)p;              p += (size_t)M_ * E_ * 2;
    _Float16* vtb = (_Float16*)p;

    cvt_x_kernel<<<dim3(M_ * E_ / 2048), dim3(256), 0, stream>>>(x, x16);
    transpose_w_kernel<<<dim3(E_ / 64, N3_ / 64), dim3(256), 0, stream>>>(Wq, wt);
    qkv_gemm32<<<dim3(512), dim3(256), 0, stream>>>(x16, wt, bq, w, qb, kb, vtb);
    attn_kernel<<<dim3(512), dim3(512), 0, stream>>>(qb, kb, vtb, w, out);
}

// Round 2
// 178.539 us; speedup vs baseline: 1.0704x; 1.0704x over previous
//
#include <hip/hip_runtime.h>
#include <math.h>

#define B_  2
#define S_  2048
#define E_  1024
#define H_  16
#define HD_ 64
#define N3_ 3072
#define M_  (B_*S_)   // 4096

typedef _Float16 h8  __attribute__((ext_vector_type(8)));
typedef _Float16 h4  __attribute__((ext_vector_type(4)));
typedef float    f4  __attribute__((ext_vector_type(4)));
typedef float    fv16 __attribute__((ext_vector_type(16)));

typedef __attribute__((address_space(3))) unsigned int       lds_u32;
typedef const __attribute__((address_space(1))) unsigned int glob_u32;

// async global->LDS, 16B/lane; global addr per-lane, LDS dest = base + lane*16.
__device__ __forceinline__ void gld16(const void* g, void* l) {
    __builtin_amdgcn_global_load_lds((glob_u32*)g, (lds_u32*)l, 16, 0, 0);
}
__device__ __forceinline__ float exp2_hw(float x) { return __builtin_amdgcn_exp2f(x); }

#define QSCALE 0.18033688011112042f   // log2(e)/8
#define RESCALE_THR 8.0f              // defer-max threshold (log2 domain): P <= 2^8

// ---------------- kernel 0b: x fp32 -> f16 ----------------
__global__ void cvt_x_kernel(const float* __restrict__ x, _Float16* __restrict__ x16) {
    int i = (blockIdx.x * 256 + threadIdx.x) * 8;
    float4 u = *(const float4*)&x[i];
    float4 v = *(const float4*)&x[i + 4];
    h8 o;
    o[0] = (_Float16)u.x; o[1] = (_Float16)u.y; o[2] = (_Float16)u.z; o[3] = (_Float16)u.w;
    o[4] = (_Float16)v.x; o[5] = (_Float16)v.y; o[6] = (_Float16)v.z; o[7] = (_Float16)v.w;
    *(h8*)&x16[i] = o;
}

// ---------------- kernel 0c: W [K][N] fp32 -> Wt [N][K] f16 ----------------
__global__ __launch_bounds__(256) void transpose_w_kernel(
        const float* __restrict__ W, _Float16* __restrict__ Wt) {
    __shared__ float T[64][65];
    int k0 = blockIdx.x * 64, n0 = blockIdx.y * 64;
    int tid = threadIdx.x;
    int r = tid >> 4, c4 = (tid & 15) * 4;
#pragma unroll
    for (int i = 0; i < 4; i++) {
        int row = r + i * 16;
        float4 u = *(const float4*)&W[(size_t)(k0 + row) * N3_ + n0 + c4];
        T[c4 + 0][row] = u.x; T[c4 + 1][row] = u.y;
        T[c4 + 2][row] = u.z; T[c4 + 3][row] = u.w;
    }
    __syncthreads();
#pragma unroll
    for (int i = 0; i < 4; i++) {
        int rn = r + i * 16;
        h4 p;
        p[0] = (_Float16)T[rn][c4 + 0]; p[1] = (_Float16)T[rn][c4 + 1];
        p[2] = (_Float16)T[rn][c4 + 2]; p[3] = (_Float16)T[rn][c4 + 3];
        *(h4*)&Wt[(size_t)(n0 + rn) * E_ + k0 + c4] = p;
    }
}

// ---------------- kernel 1: QKV GEMM, 32x32x16, 2-stage pipelined ----------
// BM=128, BN=192 (one head q|k|v), BK=64, wave = 64m x 96n.
// Swizzle: batch j stores chunk (lane&7)^(lane>>3)^(j&7); read c^(R&7)^((R>>3)&7).
__global__ __launch_bounds__(256, 2) void qkv_gemm32(
        const _Float16* __restrict__ x16, const _Float16* __restrict__ wt,
        const float* __restrict__ bq, const float* __restrict__ w,
        _Float16* __restrict__ qws, _Float16* __restrict__ kws,
        _Float16* __restrict__ vtws) {
    __shared__ __align__(16) _Float16 Ab[2][128 * 64];   // 32 KB
    __shared__ __align__(16) _Float16 Wb[2][192 * 64];   // 48 KB

    int tid = threadIdx.x;
    int wid = tid >> 6, lane = tid & 63;
    int l31 = lane & 31, hi = lane >> 5, l7 = l31 & 7;
    int srow = lane >> 3;
    int wm = wid & 1, wn = wid >> 1;

    int L = blockIdx.x;
    int head = 2 * (L & 7) + (L >> 8);   // 2 heads per XCD
    int mb = (L >> 3) & 31;
    int m0 = mb * 128;
    int n0 = head * 192;
    int b = m0 >> 11;
    int bh = b * H_ + head;
    int sblk = m0 & 2047;

    // bias folded into acc init
    fv16 acc[2][3];
#pragma unroll
    for (int ntl = 0; ntl < 3; ntl++) {
        int n_abs = wn * 96 + ntl * 32;
        int which = n_abs >> 6;
        fv16 ini;
        if (which == 2) {
            float bb = bq[n0 + n_abs + l31];
#pragma unroll
            for (int r = 0; r < 16; r++) ini[r] = bb;
        } else {
#pragma unroll
            for (int g = 0; g < 4; g++) {
                f4 bv = *(const f4*)&bq[n0 + n_abs + 8 * g + 4 * hi];
#pragma unroll
                for (int j = 0; j < 4; j++) ini[4 * g + j] = bv[j];
            }
        }
        acc[0][ntl] = ini; acc[1][ntl] = ini;
    }

    auto stage = [&](int t, int bf) {
        int k0 = t * 64;
#pragma unroll
        for (int j = 0; j < 4; j++) {
            int batch = wid * 4 + j;           // 0..15
            int row = batch * 8 + srow;
            int ch = (lane & 7) ^ srow ^ (batch & 7);
            gld16(&x16[(size_t)(m0 + row) * E_ + k0 + ch * 8], &Ab[bf][batch * 8 * 64]);
        }
#pragma unroll
        for (int j = 0; j < 6; j++) {
            int batch = wid * 6 + j;           // 0..23
            int row = batch * 8 + srow;
            int ch = (lane & 7) ^ srow ^ (batch & 7);
            gld16(&wt[(size_t)(n0 + row) * E_ + k0 + ch * 8], &Wb[bf][batch * 8 * 64]);
        }
    };

    stage(0, 0);

    for (int t = 0; t < 16; t++) {
        int bf = t & 1;
        __syncthreads();                  // drains DMA of tile t, fences buffers
        if (t < 15) stage(t + 1, bf ^ 1); // prefetch overlaps compute below
#pragma unroll
        for (int step = 0; step < 4; step++) {
            h8 af[2], wf[3];
#pragma unroll
            for (int mt = 0; mt < 2; mt++) {
                int R = wm * 64 + mt * 32 + l31;
                int ph = ((2 * step + hi) ^ l7 ^ ((mt * 4 + (l31 >> 3)) & 7)) * 8;
                af[mt] = *(const h8*)&Ab[bf][R * 64 + ph];
            }
#pragma unroll
            for (int ntl = 0; ntl < 3; ntl++) {
                int R = wn * 96 + ntl * 32 + l31;
                int ph = ((2 * step + hi) ^ l7 ^ ((wn * 12 + ntl * 4 + (l31 >> 3)) & 7)) * 8;
                wf[ntl] = *(const h8*)&Wb[bf][R * 64 + ph];
            }
#pragma unroll
            for (int ntl = 0; ntl < 3; ntl++) {
                bool isv = (wn == 1) && (ntl >= 1);
#pragma unroll
                for (int mt = 0; mt < 2; mt++) {
                    if (isv)
                        acc[mt][ntl] = __builtin_amdgcn_mfma_f32_32x32x16_f16(af[mt], wf[ntl], acc[mt][ntl], 0, 0, 0);
                    else
                        acc[mt][ntl] = __builtin_amdgcn_mfma_f32_32x32x16_f16(wf[ntl], af[mt], acc[mt][ntl], 0, 0, 0);
                }
            }
        }
    }

    // epilogue
#pragma unroll
    for (int ntl = 0; ntl < 3; ntl++) {
        int n_abs = wn * 96 + ntl * 32;
        int which = n_abs >> 6;
#pragma unroll
        for (int mt = 0; mt < 2; mt++) {
            if (which == 2) {
                // D rows = s, cols = d; V' = acc * w[s]; store Vt[d][s]
                int d = (n_abs & 63) + l31;
#pragma unroll
                for (int g = 0; g < 4; g++) {
                    int soff = wm * 64 + mt * 32 + 8 * g + 4 * hi;
                    f4 wf4 = *(const f4*)&w[m0 + soff];
                    h4 p;
#pragma unroll
                    for (int j = 0; j < 4; j++)
                        p[j] = (_Float16)(acc[mt][ntl][4 * g + j] * wf4[j]);
                    *(h4*)&vtws[((size_t)bh * 64 + d) * S_ + sblk + soff] = p;
                }
            } else {
                // D rows = d, cols = s; store [s][d]
                _Float16* dst = (which == 0) ? qws : kws;
                float scale = (which == 0) ? QSCALE : 1.0f;
                int s = sblk + wm * 64 + mt * 32 + l31;
#pragma unroll
                for (int g = 0; g < 4; g++) {
                    int d0 = (n_abs & 63) + 8 * g + 4 * hi;
                    h4 p;
#pragma unroll
                    for (int j = 0; j < 4; j++)
                        p[j] = (_Float16)(acc[mt][ntl][4 * g + j] * scale);
                    *(h4*)&dst[((size_t)bh * S_ + s) * 64 + d0] = p;
                }
            }
        }
    }
}

// ---------------- kernel 2: flash attention, pipelined, no P round-trip ----
// Wave = 32 q, block = 128 q, K-tile 64, 2-stage double-buffered staging.
// S^T = K*Q^T (32x32x16); P in regs (C k-stripe == 32x32x8 B k-stripe);
// O^T = V'^T*P (32x32x8). q = lane&31 -> softmax state lane-local.
// Serial-path cuts: tree max, defer-rescale (THR=8), lane-partial l
// (merged once in epilogue), 4-way rs partial sums, setprio on MFMA.
__global__ __launch_bounds__(256, 2) void attn_kernel(
        const _Float16* __restrict__ q, const _Float16* __restrict__ k,
        const _Float16* __restrict__ vt, const float* __restrict__ w,
        float* __restrict__ out) {
    __shared__ __align__(16) _Float16 Kb[2][64 * 64];   // 16 KB
    __shared__ __align__(16) _Float16 Vb[2][64 * 64];   // 16 KB
    __shared__ __align__(16) float lws[2048];           //  8 KB: w row (fp32)

    int tid = threadIdx.x;
    int wid = tid >> 6, lane = tid & 63;
    int l31 = lane & 31, hi = lane >> 5, l7 = l31 & 7;
    int srow = lane >> 3;
    int L = blockIdx.x;
    int bh = (L & 7) + 8 * (L >> 7);    // 16 q-tiles of a bh per XCD
    int qt = (L >> 3) & 15;
    int q0 = qt * 128;
    int b = bh >> 4, h = bh & 15;

    const _Float16* qbase = q + (size_t)bh * S_ * HD_;
    const _Float16* kbase = k + (size_t)bh * S_ * HD_;
    const _Float16* vbase = vt + (size_t)bh * HD_ * S_;
    const float* wbase = w + (size_t)b * S_;

    // stage w row (fp32, 8 KB, 8 batches of 1 KB; 2 per wave, no swizzle)
#pragma unroll
    for (int j = 0; j < 2; j++) {
        int batch = wid + 4 * j;
        gld16(&wbase[batch * 256 + lane * 4], &lws[batch * 256]);
    }

    auto stage = [&](int kt, int bf) {
        int k0 = kt * 64;
#pragma unroll
        for (int j = 0; j < 2; j++) {
            int batch = wid * 2 + j;           // 0..7
            int row = batch * 8 + srow;
            int ch = (lane & 7) ^ srow ^ (batch & 7);
            gld16(&kbase[(size_t)(k0 + row) * 64 + ch * 8], &Kb[bf][batch * 8 * 64]);
            gld16(&vbase[(size_t)row * S_ + k0 + ch * 8], &Vb[bf][batch * 8 * 64]);
        }
    };

    stage(0, 0);

    int qrow = q0 + wid * 32 + l31;
    h8 qf[4];
#pragma unroll
    for (int step = 0; step < 4; step++)
        qf[step] = *(const h8*)&qbase[(size_t)qrow * 64 + 16 * step + 8 * hi];

    fv16 o[2];
    o[0] = (fv16)0.0f; o[1] = (fv16)0.0f;
    float m_r = -INFINITY, l_r = 0.0f;   // l_r lane-partial; merged in epilogue

    for (int kt = 0; kt < 32; kt++) {
        int bf = kt & 1;
        __syncthreads();                    // drains DMA of tile kt
        if (kt < 31) stage(kt + 1, bf ^ 1); // overlaps compute below

        // ---- S^T = K*Q^T : rows k, cols q=l31 ----
        fv16 st[2];
        st[0] = (fv16)0.0f; st[1] = (fv16)0.0f;
        __builtin_amdgcn_s_setprio(1);
#pragma unroll
        for (int step = 0; step < 4; step++) {
#pragma unroll
            for (int kt2 = 0; kt2 < 2; kt2++) {
                int R = kt2 * 32 + l31;
                int ph = ((2 * step + hi) ^ l7 ^ ((kt2 * 4 + (l31 >> 3)) & 7)) * 8;
                h8 kf = *(const h8*)&Kb[bf][R * 64 + ph];
                st[kt2] = __builtin_amdgcn_mfma_f32_32x32x16_f16(kf, qf[step], st[kt2], 0, 0, 0);
            }
        }
        __builtin_amdgcn_s_setprio(0);

        // ---- online softmax (base 2), lane-local state (q = l31) ----
        // tree max over this lane's 32 S values (depth 5, not a 32-chain)
        float tm[16];
#pragma unroll
        for (int r = 0; r < 16; r++) tm[r] = fmaxf(st[0][r], st[1][r]);
#pragma unroll
        for (int r = 0; r < 8; r++) tm[r] = fmaxf(tm[r], tm[r + 8]);
#pragma unroll
        for (int r = 0; r < 4; r++) tm[r] = fmaxf(tm[r], tm[r + 4]);
        float pmax = fmaxf(fmaxf(tm[0], tm[1]), fmaxf(tm[2], tm[3]));

        // defer-rescale: only pay the cross-lane reduce + alpha + o-rescale
        // when some row's max grew by more than THR (wave-uniform branch).
        if (!__all(pmax <= m_r + RESCALE_THR)) {
            float rowmax = fmaxf(pmax, __shfl_xor(pmax, 32));
            float mnew = fmaxf(m_r, rowmax);
            float alpha = exp2_hw(m_r - mnew);   // exp2(-inf)=0 handles kt=0
            m_r = mnew;
            l_r *= alpha;
            o[0] = o[0] * alpha;
            o[1] = o[1] * alpha;
        }

        f4 rsv = (f4)0.0f;                 // 4 independent partial-sum chains
        h4 pf[2][4];
        int k0 = kt * 64;
#pragma unroll
        for (int kt2 = 0; kt2 < 2; kt2++)
#pragma unroll
            for (int g = 0; g < 4; g++) {
                f4 wv = *(const f4*)&lws[k0 + kt2 * 32 + 8 * g + 4 * hi];
                f4 e;
#pragma unroll
                for (int j = 0; j < 4; j++) {
                    float ev = exp2_hw(st[kt2][4 * g + j] - m_r);
                    e[j] = ev;
                    rsv[j] += ev * wv[j];
                }
                h4 p;
                p[0] = (_Float16)e[0]; p[1] = (_Float16)e[1];
                p[2] = (_Float16)e[2]; p[3] = (_Float16)e[3];
                pf[kt2][g] = p;
            }
        l_r += (rsv[0] + rsv[1]) + (rsv[2] + rsv[3]);

        // ---- O^T += V'^T * P (32x32x8: B k-stripe matches C regs) ----
        __builtin_amdgcn_s_setprio(1);
#pragma unroll
        for (int kt2 = 0; kt2 < 2; kt2++)
#pragma unroll
            for (int g = 0; g < 4; g++) {
                int c = 4 * kt2 + g;
#pragma unroll
                for (int dt = 0; dt < 2; dt++) {
                    int R = dt * 32 + l31;
                    int ph = (c ^ l7 ^ ((dt * 4 + (l31 >> 3)) & 7)) * 8 + hi * 4;
                    h4 vf = *(const h4*)&Vb[bf][R * 64 + ph];
                    o[dt] = __builtin_amdgcn_mfma_f32_32x32x8f16(vf, pf[kt2][g], o[dt], 0, 0, 0);
                }
            }
        __builtin_amdgcn_s_setprio(0);
    }

    // ---- epilogue: merge lane-partial l across the q-row pair, scale, store
    float lsum = l_r + __shfl_xor(l_r, 32);
    float linv = 1.0f / lsum;
    float* obase = &out[((size_t)(b * S_ + qrow)) * E_ + h * 64];
#pragma unroll
    for (int dt = 0; dt < 2; dt++)
#pragma unroll
        for (int g = 0; g < 4; g++) {
            int d0 = dt * 32 + 8 * g + 4 * hi;
            f4 ov;
#pragma unroll
            for (int j = 0; j < 4; j++) ov[j] = o[dt][4 * g + j] * linv;
            *(f4*)&obase[d0] = ov;
        }
}

extern "C" void kernel_launch(void* const* d_in, const int* in_sizes, int n_in,
                              void* d_out, int out_size, void* d_ws, size_t ws_size,
                              hipStream_t stream) {
    const float* x  = (const float*)d_in[0];
    const float* w  = (const float*)d_in[1];
    const float* Wq = (const float*)d_in[2];
    const float* bq = (const float*)d_in[3];
    float* out = (float*)d_out;

    char* p = (char*)d_ws;
    _Float16* x16 = (_Float16*)p;              p += (size_t)M_ * E_ * 2;
    _Float16* wt  = (_Float16*)p;              p += (size_t)E_ * N3_ * 2;
    _Float16* qb  = (_Float16*)p;              p += (size_t)M_ * E_ * 2;
    _Float16* kb  = (_Float16*)p;              p += (size_t)M_ * E_ * 2;
    _Float16* vtb = (_Float16*)p;

    cvt_x_kernel<<<dim3(M_ * E_ / 2048), dim3(256), 0, stream>>>(x, x16);
    transpose_w_kernel<<<dim3(E_ / 64, N3_ / 64), dim3(256), 0, stream>>>(Wq, wt);
    qkv_gemm32<<<dim3(512), dim3(256), 0, stream>>>(x16, wt, bq, w, qb, kb, vtb);
    attn_kernel<<<dim3(512), dim3(256), 0, stream>>>(qb, kb, vtb, w, out);
}